// Round 1
// baseline (422.025 us; speedup 1.0000x reference)
//
#include <hip/hip_runtime.h>
#include <hip/hip_bf16.h>

#define S_LEN 4096
#define DM    768
#define NH    12
#define DKH   64

typedef __attribute__((ext_vector_type(8))) short short8;
typedef __attribute__((ext_vector_type(4))) float f32x4;

__device__ __forceinline__ short f2bf(float f) {
    union { float f; unsigned u; } v; v.f = f;
    unsigned r = (v.u + 0x7FFFu + ((v.u >> 16) & 1u)) >> 16;
    return (short)r;
}

#define MFMA16(a, b, c) __builtin_amdgcn_mfma_f32_16x16x32_bf16((a), (b), (c), 0, 0, 0)

// ---------------------------------------------------------------- converts
__global__ __launch_bounds__(256) void to_bf16_k(const float* __restrict__ src,
                                                 short* __restrict__ dst, int n) {
    int i = (blockIdx.x * 256 + threadIdx.x) * 4;
    if (i >= n) return;
    float4 v = *reinterpret_cast<const float4*>(src + i);
    short4 o;
    o.x = f2bf(v.x); o.y = f2bf(v.y); o.z = f2bf(v.z); o.w = f2bf(v.w);
    *reinterpret_cast<short4*>(dst + i) = o;
}

__global__ __launch_bounds__(256) void rope_table_k(const int* __restrict__ pos,
                                                    float2* __restrict__ rt) {
    int idx = blockIdx.x * 256 + threadIdx.x;
    if (idx >= S_LEN * 32) return;
    int s = idx >> 5, i = idx & 31;
    int p = pos[s]; p = p < 0 ? 0 : (p > 4095 ? 4095 : p);
    double inv = pow(10000.0, -(double)i / 32.0);
    float ang = (float)((double)p * inv);
    rt[idx] = make_float2(cosf(ang), sinf(ang));
}

// ---------------------------------------------------------------- GEMM core
// Y[m0+128][n0+128] tile of A(row-major, K=768) x B(row-major, K=768)^T
// 4 waves in 2x2, each 64x64 via 4x4 frags of 16x16x32 bf16 MFMA.
__device__ __forceinline__ void gemm_mainloop(const short* __restrict__ A,
                                              const short* __restrict__ B,
                                              short (*Al)[40], short (*Bl)[40],
                                              int m0, int n0, int t,
                                              f32x4 acc[4][4]) {
    const int wave = t >> 6, lane = t & 63;
    const int wm = (wave >> 1) * 64, wn = (wave & 1) * 64;
    const int l15 = lane & 15, lg = lane >> 4;
    for (int k0 = 0; k0 < DM; k0 += 32) {
        __syncthreads();
#pragma unroll
        for (int i = 0; i < 2; ++i) {
            int c = t + i * 256;
            int row = c >> 2, kg = c & 3;
            *reinterpret_cast<short8*>(&Al[row][kg * 8]) =
                *reinterpret_cast<const short8*>(&A[(m0 + row) * DM + k0 + kg * 8]);
            *reinterpret_cast<short8*>(&Bl[row][kg * 8]) =
                *reinterpret_cast<const short8*>(&B[(n0 + row) * DM + k0 + kg * 8]);
        }
        __syncthreads();
        short8 af[4], bf[4];
#pragma unroll
        for (int m = 0; m < 4; ++m)
            af[m] = *reinterpret_cast<const short8*>(&Al[wm + m * 16 + l15][lg * 8]);
#pragma unroll
        for (int n = 0; n < 4; ++n)
            bf[n] = *reinterpret_cast<const short8*>(&Bl[wn + n * 16 + l15][lg * 8]);
#pragma unroll
        for (int m = 0; m < 4; ++m)
#pragma unroll
            for (int n = 0; n < 4; ++n)
                acc[m][n] = MFMA16(af[m], bf[n], acc[m][n]);
    }
}

// QKV projection + fused RoPE epilogue. grid = (6, 32, 3)
__global__ __launch_bounds__(256) void gemm_qkv_k(
    const short* __restrict__ Xbf, const short* __restrict__ Wq,
    const short* __restrict__ Wk, const short* __restrict__ Wv,
    const float2* __restrict__ rt,
    short* __restrict__ Q, short* __restrict__ K, short* __restrict__ V) {
    __shared__ __align__(16) short Al[128][40];
    __shared__ __align__(16) short Bl[128][40];
    const int mat = blockIdx.z;
    const short* B = mat == 0 ? Wq : (mat == 1 ? Wk : Wv);
    short* Out = mat == 0 ? Q : (mat == 1 ? K : V);
    const int m0 = blockIdx.y * 128, n0 = blockIdx.x * 128;
    const int t = threadIdx.x;
    f32x4 acc[4][4] = {};
    gemm_mainloop(Xbf, B, Al, Bl, m0, n0, t, acc);
    const int wave = t >> 6, lane = t & 63;
    const int wm = (wave >> 1) * 64, wn = (wave & 1) * 64;
    const int l15 = lane & 15, lg = lane >> 4;
    const bool dorope = (mat < 2);
#pragma unroll
    for (int m = 0; m < 4; ++m) {
#pragma unroll
        for (int n = 0; n < 4; ++n) {
            int col = n0 + wn + n * 16 + l15;
            int h = col >> 6, d = col & 63;
#pragma unroll
            for (int j = 0; j < 4; ++j) {
                int srow = m0 + wm + m * 16 + lg * 4 + j;
                float v = acc[m][n][j];
                float other = __shfl_xor(v, 1);  // partner col (d^1), same row
                if (dorope) {
                    float2 cs = rt[srow * 32 + (d >> 1)];
                    v = (d & 1) ? (other * cs.y + v * cs.x)   // x0*sin + x1*cos
                                : (v * cs.x - other * cs.y);  // x0*cos - x1*sin
                }
                Out[(h * S_LEN + srow) * DKH + d] = f2bf(v);
            }
        }
    }
}

// Output projection: Ab(4096x768 bf16) x Wo^T -> fp32. grid = (6, 32)
__global__ __launch_bounds__(256) void gemm_out_k(const short* __restrict__ Ab,
                                                  const short* __restrict__ Wo,
                                                  float* __restrict__ out) {
    __shared__ __align__(16) short Al[128][40];
    __shared__ __align__(16) short Bl[128][40];
    const int m0 = blockIdx.y * 128, n0 = blockIdx.x * 128;
    const int t = threadIdx.x;
    f32x4 acc[4][4] = {};
    gemm_mainloop(Ab, Wo, Al, Bl, m0, n0, t, acc);
    const int wave = t >> 6, lane = t & 63;
    const int wm = (wave >> 1) * 64, wn = (wave & 1) * 64;
    const int l15 = lane & 15, lg = lane >> 4;
#pragma unroll
    for (int m = 0; m < 4; ++m)
#pragma unroll
        for (int n = 0; n < 4; ++n)
#pragma unroll
            for (int j = 0; j < 4; ++j) {
                int srow = m0 + wm + m * 16 + lg * 4 + j;
                int col = n0 + wn + n * 16 + l15;
                out[srow * DM + col] = acc[m][n][j];
            }
}

// V (H,S,64) -> Vt (H,64,S). grid = (12, 64)
__global__ __launch_bounds__(256) void transpose_v_k(const short* __restrict__ V,
                                                     short* __restrict__ Vt) {
    __shared__ __align__(16) short T[64][72];
    const int h = blockIdx.x, sb = blockIdx.y;
    const int t = threadIdx.x;
    const int s0 = sb * 64;
#pragma unroll
    for (int i = 0; i < 2; ++i) {
        int c = t + i * 256;
        int sr = c >> 3, dg = c & 7;
        short8 v = *reinterpret_cast<const short8*>(&V[(h * S_LEN + s0 + sr) * DKH + dg * 8]);
#pragma unroll
        for (int e = 0; e < 8; ++e) T[dg * 8 + e][sr] = v[e];
    }
    __syncthreads();
#pragma unroll
    for (int i = 0; i < 2; ++i) {
        int c = t + i * 256;
        int dr = c >> 3, sg = c & 7;
        *reinterpret_cast<short8*>(&Vt[(h * DKH + dr) * S_LEN + s0 + sg * 8]) =
            *reinterpret_cast<const short8*>(&T[dr][sg * 8]);
    }
}

// Causal flash attention. grid = (64 qblocks, 12 heads), 4 waves x 16 q-rows.
__global__ __launch_bounds__(256) void attn_k(const short* __restrict__ Q,
                                              const short* __restrict__ K,
                                              const short* __restrict__ Vt,
                                              short* __restrict__ Aout) {
    const int qb = blockIdx.x, h = blockIdx.y;
    const int t = threadIdx.x;
    const int wave = t >> 6, lane = t & 63;
    const int l15 = lane & 15, lg = lane >> 4;
    const int q0 = qb * 64 + wave * 16;

    __shared__ __align__(16) short Pl[4][16][72];  // per-wave P scratch

    short8 qf[2];
#pragma unroll
    for (int ks = 0; ks < 2; ++ks)
        qf[ks] = *reinterpret_cast<const short8*>(
            &Q[(h * S_LEN + q0 + l15) * DKH + ks * 32 + lg * 8]);

    f32x4 o[4] = {};
    float mrow[4], lrow[4];
#pragma unroll
    for (int j = 0; j < 4; ++j) { mrow[j] = -INFINITY; lrow[j] = 0.f; }

    const float scale = 0.125f;  // 1/sqrt(64)
    const int kvmax = qb * 64;
    for (int kv0 = 0; kv0 <= kvmax; kv0 += 64) {
        // ---- S = (Q K^T) * scale, causal mask
        f32x4 s[4] = {};
#pragma unroll
        for (int n = 0; n < 4; ++n)
#pragma unroll
            for (int ks = 0; ks < 2; ++ks) {
                short8 kf = *reinterpret_cast<const short8*>(
                    &K[(h * S_LEN + kv0 + n * 16 + l15) * DKH + ks * 32 + lg * 8]);
                s[n] = MFMA16(qf[ks], kf, s[n]);
            }
#pragma unroll
        for (int n = 0; n < 4; ++n) {
            int col = kv0 + n * 16 + l15;
#pragma unroll
            for (int j = 0; j < 4; ++j) {
                int row = q0 + lg * 4 + j;
                float v = s[n][j] * scale;
                if (col > row) v = -INFINITY;
                s[n][j] = v;
            }
        }
        // ---- online softmax (16-lane groups share the same 4 rows)
#pragma unroll
        for (int j = 0; j < 4; ++j) {
            float v = fmaxf(fmaxf(s[0][j], s[1][j]), fmaxf(s[2][j], s[3][j]));
            v = fmaxf(v, __shfl_xor(v, 1));
            v = fmaxf(v, __shfl_xor(v, 2));
            v = fmaxf(v, __shfl_xor(v, 4));
            v = fmaxf(v, __shfl_xor(v, 8));
            float mnew = fmaxf(mrow[j], v);
            float alpha = __expf(mrow[j] - mnew);
            mrow[j] = mnew;
            float rs = 0.f;
#pragma unroll
            for (int n = 0; n < 4; ++n) {
                float p = __expf(s[n][j] - mnew);
                s[n][j] = p;
                rs += p;
            }
            rs += __shfl_xor(rs, 1);
            rs += __shfl_xor(rs, 2);
            rs += __shfl_xor(rs, 4);
            rs += __shfl_xor(rs, 8);
            lrow[j] = lrow[j] * alpha + rs;
#pragma unroll
            for (int n = 0; n < 4; ++n) o[n][j] *= alpha;
        }
        // ---- P (C-layout) -> LDS -> A-layout fragments
#pragma unroll
        for (int n = 0; n < 4; ++n)
#pragma unroll
            for (int j = 0; j < 4; ++j)
                Pl[wave][lg * 4 + j][n * 16 + l15] = f2bf(s[n][j]);
        // same-wave LDS RAW: compiler inserts lgkmcnt wait
#pragma unroll
        for (int ks = 0; ks < 2; ++ks) {
            short8 pa = *reinterpret_cast<const short8*>(&Pl[wave][l15][ks * 32 + lg * 8]);
#pragma unroll
            for (int n = 0; n < 4; ++n) {
                short8 vf = *reinterpret_cast<const short8*>(
                    &Vt[(h * DKH + n * 16 + l15) * S_LEN + kv0 + ks * 32 + lg * 8]);
                o[n] = MFMA16(pa, vf, o[n]);
            }
        }
    }
    // ---- normalize + store (S,768) head-major
#pragma unroll
    for (int n = 0; n < 4; ++n)
#pragma unroll
        for (int j = 0; j < 4; ++j) {
            float v = o[n][j] / lrow[j];
            int srow = q0 + lg * 4 + j;
            int d = n * 16 + l15;
            Aout[srow * DM + h * DKH + d] = f2bf(v);
        }
}

// ---------------------------------------------------------------- launcher
extern "C" void kernel_launch(void* const* d_in, const int* in_sizes, int n_in,
                              void* d_out, int out_size, void* d_ws, size_t ws_size,
                              hipStream_t stream) {
    const float* X  = (const float*)d_in[0];
    const int*   pos = (const int*)d_in[1];
    const float* Wq = (const float*)d_in[2];
    const float* Wk = (const float*)d_in[3];
    const float* Wv = (const float*)d_in[4];
    const float* Wo = (const float*)d_in[5];
    float* out = (float*)d_out;

    char* ws = (char*)d_ws;
    short* Xbf = (short*)ws;  ws += (size_t)S_LEN * DM * 2;
    short* Wqb = (short*)ws;  ws += (size_t)DM * DM * 2;
    short* Wkb = (short*)ws;  ws += (size_t)DM * DM * 2;
    short* Wvb = (short*)ws;  ws += (size_t)DM * DM * 2;
    short* Wob = (short*)ws;  ws += (size_t)DM * DM * 2;
    float2* rt = (float2*)ws; ws += (size_t)S_LEN * 32 * 8;
    short* Qb  = (short*)ws;  ws += (size_t)NH * S_LEN * DKH * 2;
    short* Kb  = (short*)ws;  ws += (size_t)NH * S_LEN * DKH * 2;
    short* Vb  = (short*)ws;  ws += (size_t)NH * S_LEN * DKH * 2;
    short* Vtb = (short*)ws;  ws += (size_t)NH * S_LEN * DKH * 2;
    short* Ab  = (short*)ws;  ws += (size_t)S_LEN * DM * 2;

    to_bf16_k<<<(S_LEN * DM / 4 + 255) / 256, 256, 0, stream>>>(X, Xbf, S_LEN * DM);
    to_bf16_k<<<(DM * DM / 4 + 255) / 256, 256, 0, stream>>>(Wq, Wqb, DM * DM);
    to_bf16_k<<<(DM * DM / 4 + 255) / 256, 256, 0, stream>>>(Wk, Wkb, DM * DM);
    to_bf16_k<<<(DM * DM / 4 + 255) / 256, 256, 0, stream>>>(Wv, Wvb, DM * DM);
    to_bf16_k<<<(DM * DM / 4 + 255) / 256, 256, 0, stream>>>(Wo, Wob, DM * DM);
    rope_table_k<<<(S_LEN * 32 + 255) / 256, 256, 0, stream>>>(pos, rt);

    gemm_qkv_k<<<dim3(6, 32, 3), 256, 0, stream>>>(Xbf, Wqb, Wkb, Wvb, rt, Qb, Kb, Vb);
    transpose_v_k<<<dim3(NH, 64), 256, 0, stream>>>(Vb, Vtb);
    attn_k<<<dim3(64, NH), 256, 0, stream>>>(Qb, Kb, Vtb, Ab);
    gemm_out_k<<<dim3(6, 32), 256, 0, stream>>>(Ab, Wob, out);
}

// Round 2
// 267.520 us; speedup vs baseline: 1.5775x; 1.5775x over previous
//
#include <hip/hip_runtime.h>
#include <hip/hip_bf16.h>

#define S_LEN 4096
#define DM    768
#define NH    12
#define DKH   64

typedef __attribute__((ext_vector_type(8))) short short8;
typedef __attribute__((ext_vector_type(4))) float f32x4;

__device__ __forceinline__ short f2bf(float f) {
    union { float f; unsigned u; } v; v.f = f;
    unsigned r = (v.u + 0x7FFFu + ((v.u >> 16) & 1u)) >> 16;
    return (short)r;
}

#define MFMA16(a, b, c) __builtin_amdgcn_mfma_f32_16x16x32_bf16((a), (b), (c), 0, 0, 0)

// ---------------------------------------------------------------- converts
__global__ __launch_bounds__(256) void to_bf16_k(const float* __restrict__ src,
                                                 short* __restrict__ dst, int n) {
    int i = (blockIdx.x * 256 + threadIdx.x) * 4;
    if (i >= n) return;
    float4 v = *reinterpret_cast<const float4*>(src + i);
    short4 o;
    o.x = f2bf(v.x); o.y = f2bf(v.y); o.z = f2bf(v.z); o.w = f2bf(v.w);
    *reinterpret_cast<short4*>(dst + i) = o;
}

__global__ __launch_bounds__(256) void rope_table_k(const int* __restrict__ pos,
                                                    float2* __restrict__ rt) {
    int idx = blockIdx.x * 256 + threadIdx.x;
    if (idx >= S_LEN * 32) return;
    int s = idx >> 5, i = idx & 31;
    int p = pos[s]; p = p < 0 ? 0 : (p > 4095 ? 4095 : p);
    double inv = pow(10000.0, -(double)i / 32.0);
    float ang = (float)((double)p * inv);
    rt[idx] = make_float2(cosf(ang), sinf(ang));
}

// ---------------------------------------------------------------- GEMM core
__device__ __forceinline__ void gemm_mainloop(const short* __restrict__ A,
                                              const short* __restrict__ B,
                                              short (*Al)[40], short (*Bl)[40],
                                              int m0, int n0, int t,
                                              f32x4 acc[4][4]) {
    const int wave = t >> 6, lane = t & 63;
    const int wm = (wave >> 1) * 64, wn = (wave & 1) * 64;
    const int l15 = lane & 15, lg = lane >> 4;
    for (int k0 = 0; k0 < DM; k0 += 32) {
        __syncthreads();
#pragma unroll
        for (int i = 0; i < 2; ++i) {
            int c = t + i * 256;
            int row = c >> 2, kg = c & 3;
            *reinterpret_cast<short8*>(&Al[row][kg * 8]) =
                *reinterpret_cast<const short8*>(&A[(m0 + row) * DM + k0 + kg * 8]);
            *reinterpret_cast<short8*>(&Bl[row][kg * 8]) =
                *reinterpret_cast<const short8*>(&B[(n0 + row) * DM + k0 + kg * 8]);
        }
        __syncthreads();
        short8 af[4], bf[4];
#pragma unroll
        for (int m = 0; m < 4; ++m)
            af[m] = *reinterpret_cast<const short8*>(&Al[wm + m * 16 + l15][lg * 8]);
#pragma unroll
        for (int n = 0; n < 4; ++n)
            bf[n] = *reinterpret_cast<const short8*>(&Bl[wn + n * 16 + l15][lg * 8]);
#pragma unroll
        for (int m = 0; m < 4; ++m)
#pragma unroll
            for (int n = 0; n < 4; ++n)
                acc[m][n] = MFMA16(af[m], bf[n], acc[m][n]);
    }
}

// QKV projection + fused RoPE (+1/8 scale on Q). grid = (6, 32, 3)
__global__ __launch_bounds__(256) void gemm_qkv_k(
    const short* __restrict__ Xbf, const short* __restrict__ Wq,
    const short* __restrict__ Wk, const short* __restrict__ Wv,
    const float2* __restrict__ rt,
    short* __restrict__ Q, short* __restrict__ K, short* __restrict__ V) {
    __shared__ __align__(16) short Al[128][40];
    __shared__ __align__(16) short Bl[128][40];
    const int mat = blockIdx.z;
    const short* B = mat == 0 ? Wq : (mat == 1 ? Wk : Wv);
    short* Out = mat == 0 ? Q : (mat == 1 ? K : V);
    const int m0 = blockIdx.y * 128, n0 = blockIdx.x * 128;
    const int t = threadIdx.x;
    f32x4 acc[4][4] = {};
    gemm_mainloop(Xbf, B, Al, Bl, m0, n0, t, acc);
    const int wave = t >> 6, lane = t & 63;
    const int wm = (wave >> 1) * 64, wn = (wave & 1) * 64;
    const int l15 = lane & 15, lg = lane >> 4;
    const bool dorope = (mat < 2);
#pragma unroll
    for (int m = 0; m < 4; ++m) {
#pragma unroll
        for (int n = 0; n < 4; ++n) {
            int col = n0 + wn + n * 16 + l15;
            int h = col >> 6, d = col & 63;
#pragma unroll
            for (int j = 0; j < 4; ++j) {
                int srow = m0 + wm + m * 16 + lg * 4 + j;
                float v = acc[m][n][j];
                float other = __shfl_xor(v, 1);
                if (dorope) {
                    float2 cs = rt[srow * 32 + (d >> 1)];
                    v = (d & 1) ? (other * cs.y + v * cs.x)
                                : (v * cs.x - other * cs.y);
                }
                if (mat == 0) v *= 0.125f;  // fold 1/sqrt(dk) into Q
                Out[(h * S_LEN + srow) * DKH + d] = f2bf(v);
            }
        }
    }
}

// Output projection. grid = (6, 32)
__global__ __launch_bounds__(256) void gemm_out_k(const short* __restrict__ Ab,
                                                  const short* __restrict__ Wo,
                                                  float* __restrict__ out) {
    __shared__ __align__(16) short Al[128][40];
    __shared__ __align__(16) short Bl[128][40];
    const int m0 = blockIdx.y * 128, n0 = blockIdx.x * 128;
    const int t = threadIdx.x;
    f32x4 acc[4][4] = {};
    gemm_mainloop(Ab, Wo, Al, Bl, m0, n0, t, acc);
    const int wave = t >> 6, lane = t & 63;
    const int wm = (wave >> 1) * 64, wn = (wave & 1) * 64;
    const int l15 = lane & 15, lg = lane >> 4;
#pragma unroll
    for (int m = 0; m < 4; ++m)
#pragma unroll
        for (int n = 0; n < 4; ++n)
#pragma unroll
            for (int j = 0; j < 4; ++j) {
                int srow = m0 + wm + m * 16 + lg * 4 + j;
                int col = n0 + wn + n * 16 + l15;
                out[srow * DM + col] = acc[m][n][j];
            }
}

// V (H,S,64) -> Vt (H,64,S). grid = (12, 64)
__global__ __launch_bounds__(256) void transpose_v_k(const short* __restrict__ V,
                                                     short* __restrict__ Vt) {
    __shared__ __align__(16) short T[64][72];
    const int h = blockIdx.x, sb = blockIdx.y;
    const int t = threadIdx.x;
    const int s0 = sb * 64;
#pragma unroll
    for (int i = 0; i < 2; ++i) {
        int c = t + i * 256;
        int sr = c >> 3, dg = c & 7;
        short8 v = *reinterpret_cast<const short8*>(&V[(h * S_LEN + s0 + sr) * DKH + dg * 8]);
#pragma unroll
        for (int e = 0; e < 8; ++e) T[dg * 8 + e][sr] = v[e];
    }
    __syncthreads();
#pragma unroll
    for (int i = 0; i < 2; ++i) {
        int c = t + i * 256;
        int dr = c >> 3, sg = c & 7;
        *reinterpret_cast<short8*>(&Vt[(h * DKH + dr) * S_LEN + s0 + sg * 8]) =
            *reinterpret_cast<const short8*>(&T[dr][sg * 8]);
    }
}

// ---------------------------------------------------------------- attention
// Stage a 64x64 bf16 tile (8KB) into LDS via global_load_lds, with the
// XOR chunk-swizzle applied on the GLOBAL source (linear LDS dest, rule #21):
// LDS(row, chunk m) holds global chunk m ^ (row&7). Read side XORs the same.
__device__ __forceinline__ void stage64(const short* __restrict__ gRow0,
                                        int rowStride, short* lbuf,
                                        int wave, int lane) {
#pragma unroll
    for (int i = 0; i < 2; ++i) {
        int c = wave + i * 4;                     // chunk-of-1KB 0..7
        int row = c * 8 + (lane >> 3);            // tile row 0..63
        int gch = (lane & 7) ^ (lane >> 3);       // swizzled 16B chunk in row
        const short* src = gRow0 + (long)row * rowStride + gch * 8;
        short* dst = lbuf + c * 512 + lane * 8;   // linear: row*64 + chunk*8
        __builtin_amdgcn_global_load_lds(
            (const __attribute__((address_space(1))) void*)src,
            (__attribute__((address_space(3))) void*)dst, 16, 0, 0);
    }
}

// Causal flash attention. grid = 32*12 blocks (heavy-first), 4 waves,
// 128 q-rows/block, 32 q-rows/wave (2 frags), KV tile = 64, double-buffered.
__global__ __launch_bounds__(256) void attn_k(const short* __restrict__ Q,
                                              const short* __restrict__ K,
                                              const short* __restrict__ Vt,
                                              short* __restrict__ Aout) {
    const int bx = blockIdx.x;
    const int h = bx % NH;
    const int qb = (S_LEN / 128 - 1) - (bx / NH);   // heaviest blocks first
    const int qbase = qb * 128;
    const int t = threadIdx.x;
    const int wave = t >> 6, lane = t & 63;
    const int l15 = lane & 15, lg = lane >> 4;
    const int q0w = qbase + wave * 32;

    __shared__ __align__(16) short Kl[2][64][64];
    __shared__ __align__(16) short Vl[2][64][64];
    __shared__ __align__(16) short Pl[4][32][72];

    short8 qf[2][2];
#pragma unroll
    for (int f = 0; f < 2; ++f)
#pragma unroll
        for (int ks = 0; ks < 2; ++ks)
            qf[f][ks] = *reinterpret_cast<const short8*>(
                &Q[(h * S_LEN + q0w + f * 16 + l15) * DKH + ks * 32 + lg * 8]);

    f32x4 o[2][4] = {};
    float mrow[2][4], lrow[2][4];
#pragma unroll
    for (int f = 0; f < 2; ++f)
#pragma unroll
        for (int j = 0; j < 4; ++j) { mrow[f][j] = -INFINITY; lrow[f][j] = 0.f; }

    const int nt = qb * 2 + 2;
    stage64(&K[(size_t)h * S_LEN * DKH], DKH, &Kl[0][0][0], wave, lane);
    stage64(&Vt[(size_t)h * DKH * S_LEN], S_LEN, &Vl[0][0][0], wave, lane);
    __syncthreads();
    int cur = 0;

    for (int tile = 0; tile < nt; ++tile) {
        const int kv0 = tile * 64;
        if (tile + 1 < nt) {
            const int kvn = kv0 + 64;
            stage64(&K[((size_t)h * S_LEN + kvn) * DKH], DKH, &Kl[cur ^ 1][0][0], wave, lane);
            stage64(&Vt[(size_t)h * DKH * S_LEN + kvn], S_LEN, &Vl[cur ^ 1][0][0], wave, lane);
        }
        const char* Kb = (const char*)&Kl[cur][0][0];
        const char* Vb = (const char*)&Vl[cur][0][0];

        // ---- S = Q K^T (Q pre-scaled); K frag reused across both q-frags
        f32x4 s[2][4] = {};
#pragma unroll
        for (int ks = 0; ks < 2; ++ks)
#pragma unroll
            for (int n = 0; n < 4; ++n) {
                int r = n * 16 + l15;
                int c8 = (ks * 4 + lg) ^ (r & 7);
                short8 kf = *reinterpret_cast<const short8*>(Kb + r * 128 + c8 * 16);
                s[0][n] = MFMA16(qf[0][ks], kf, s[0][n]);
                s[1][n] = MFMA16(qf[1][ks], kf, s[1][n]);
            }

        // ---- mask + online softmax per frag
#pragma unroll
        for (int f = 0; f < 2; ++f) {
            const int q0f = q0w + f * 16;
            if (kv0 + 63 > q0f) {
#pragma unroll
                for (int n = 0; n < 4; ++n) {
                    int col = kv0 + n * 16 + l15;
#pragma unroll
                    for (int j = 0; j < 4; ++j)
                        if (col > q0f + lg * 4 + j) s[f][n][j] = -INFINITY;
                }
            }
#pragma unroll
            for (int j = 0; j < 4; ++j) {
                float v = fmaxf(fmaxf(s[f][0][j], s[f][1][j]),
                                fmaxf(s[f][2][j], s[f][3][j]));
                v = fmaxf(v, __shfl_xor(v, 1));
                v = fmaxf(v, __shfl_xor(v, 2));
                v = fmaxf(v, __shfl_xor(v, 4));
                v = fmaxf(v, __shfl_xor(v, 8));
                float mnew = fmaxf(mrow[f][j], v);
                float alpha = __expf(mrow[f][j] - mnew);
                mrow[f][j] = mnew;
                float rs = 0.f;
#pragma unroll
                for (int n = 0; n < 4; ++n) {
                    float p = __expf(s[f][n][j] - mnew);
                    s[f][n][j] = p;
                    rs += p;
                }
                rs += __shfl_xor(rs, 1);
                rs += __shfl_xor(rs, 2);
                rs += __shfl_xor(rs, 4);
                rs += __shfl_xor(rs, 8);
                lrow[f][j] = lrow[f][j] * alpha + rs;
#pragma unroll
                for (int n = 0; n < 4; ++n) o[f][n][j] *= alpha;
            }
            // C-layout -> LDS for A-layout repack
#pragma unroll
            for (int n = 0; n < 4; ++n)
#pragma unroll
                for (int j = 0; j < 4; ++j)
                    Pl[wave][f * 16 + lg * 4 + j][n * 16 + l15] = f2bf(s[f][n][j]);
        }

        // ---- O += P V   (V frag reused across both q-frags)
#pragma unroll
        for (int ks = 0; ks < 2; ++ks) {
            short8 pa0 = *reinterpret_cast<const short8*>(&Pl[wave][l15][ks * 32 + lg * 8]);
            short8 pa1 = *reinterpret_cast<const short8*>(&Pl[wave][16 + l15][ks * 32 + lg * 8]);
#pragma unroll
            for (int n = 0; n < 4; ++n) {
                int r = n * 16 + l15;
                int c8 = (ks * 4 + lg) ^ (r & 7);
                short8 vf = *reinterpret_cast<const short8*>(Vb + r * 128 + c8 * 16);
                o[0][n] = MFMA16(pa0, vf, o[0][n]);
                o[1][n] = MFMA16(pa1, vf, o[1][n]);
            }
        }
        __syncthreads();   // drains staged loads; protects buffers both ways
        cur ^= 1;
    }

    // ---- normalize + store (S,768) head-major
#pragma unroll
    for (int f = 0; f < 2; ++f)
#pragma unroll
        for (int n = 0; n < 4; ++n)
#pragma unroll
            for (int j = 0; j < 4; ++j) {
                float v = o[f][n][j] / lrow[f][j];
                int srow = q0w + f * 16 + lg * 4 + j;
                Aout[srow * DM + h * DKH + n * 16 + l15] = f2bf(v);
            }
}

// ---------------------------------------------------------------- launcher
extern "C" void kernel_launch(void* const* d_in, const int* in_sizes, int n_in,
                              void* d_out, int out_size, void* d_ws, size_t ws_size,
                              hipStream_t stream) {
    const float* X  = (const float*)d_in[0];
    const int*   pos = (const int*)d_in[1];
    const float* Wq = (const float*)d_in[2];
    const float* Wk = (const float*)d_in[3];
    const float* Wv = (const float*)d_in[4];
    const float* Wo = (const float*)d_in[5];
    float* out = (float*)d_out;

    char* ws = (char*)d_ws;
    short* Xbf = (short*)ws;  ws += (size_t)S_LEN * DM * 2;
    short* Wqb = (short*)ws;  ws += (size_t)DM * DM * 2;
    short* Wkb = (short*)ws;  ws += (size_t)DM * DM * 2;
    short* Wvb = (short*)ws;  ws += (size_t)DM * DM * 2;
    short* Wob = (short*)ws;  ws += (size_t)DM * DM * 2;
    float2* rt = (float2*)ws; ws += (size_t)S_LEN * 32 * 8;
    short* Qb  = (short*)ws;  ws += (size_t)NH * S_LEN * DKH * 2;
    short* Kb  = (short*)ws;  ws += (size_t)NH * S_LEN * DKH * 2;
    short* Vb  = (short*)ws;  ws += (size_t)NH * S_LEN * DKH * 2;
    short* Vtb = (short*)ws;  ws += (size_t)NH * S_LEN * DKH * 2;
    short* Ab  = (short*)ws;  ws += (size_t)S_LEN * DM * 2;

    to_bf16_k<<<(S_LEN * DM / 4 + 255) / 256, 256, 0, stream>>>(X, Xbf, S_LEN * DM);
    to_bf16_k<<<(DM * DM / 4 + 255) / 256, 256, 0, stream>>>(Wq, Wqb, DM * DM);
    to_bf16_k<<<(DM * DM / 4 + 255) / 256, 256, 0, stream>>>(Wk, Wkb, DM * DM);
    to_bf16_k<<<(DM * DM / 4 + 255) / 256, 256, 0, stream>>>(Wv, Wvb, DM * DM);
    to_bf16_k<<<(DM * DM / 4 + 255) / 256, 256, 0, stream>>>(Wo, Wob, DM * DM);
    rope_table_k<<<(S_LEN * 32 + 255) / 256, 256, 0, stream>>>(pos, rt);

    gemm_qkv_k<<<dim3(6, 32, 3), 256, 0, stream>>>(Xbf, Wqb, Wkb, Wvb, rt, Qb, Kb, Vb);
    transpose_v_k<<<dim3(NH, 64), 256, 0, stream>>>(Vb, Vtb);
    attn_k<<<dim3(32 * NH), 256, 0, stream>>>(Qb, Kb, Vtb, Ab);
    gemm_out_k<<<dim3(6, 32), 256, 0, stream>>>(Ab, Wob, out);
}

// Round 3
// 175.312 us; speedup vs baseline: 2.4073x; 1.5260x over previous
//
#include <hip/hip_runtime.h>
#include <hip/hip_bf16.h>

#define S_LEN 4096
#define DM    768
#define NH    12
#define DKH   64

typedef __attribute__((ext_vector_type(8))) short short8;
typedef __attribute__((ext_vector_type(4))) float f32x4;

__device__ __forceinline__ short f2bf(float f) {
    union { float f; unsigned u; } v; v.f = f;
    unsigned r = (v.u + 0x7FFFu + ((v.u >> 16) & 1u)) >> 16;
    return (short)r;
}

#define MFMA16(a, b, c) __builtin_amdgcn_mfma_f32_16x16x32_bf16((a), (b), (c), 0, 0, 0)

// ---------------------------------------------------------------- converts
__global__ __launch_bounds__(256) void to_bf16_k(const float* __restrict__ src,
                                                 short* __restrict__ dst, int n) {
    int i = (blockIdx.x * 256 + threadIdx.x) * 4;
    if (i >= n) return;
    float4 v = *reinterpret_cast<const float4*>(src + i);
    short4 o;
    o.x = f2bf(v.x); o.y = f2bf(v.y); o.z = f2bf(v.z); o.w = f2bf(v.w);
    *reinterpret_cast<short4*>(dst + i) = o;
}

__global__ __launch_bounds__(256) void rope_table_k(const int* __restrict__ pos,
                                                    float2* __restrict__ rt) {
    int idx = blockIdx.x * 256 + threadIdx.x;
    if (idx >= S_LEN * 32) return;
    int s = idx >> 5, i = idx & 31;
    int p = pos[s]; p = p < 0 ? 0 : (p > 4095 ? 4095 : p);
    double inv = pow(10000.0, -(double)i / 32.0);
    float ang = (float)((double)p * inv);
    rt[idx] = make_float2(cosf(ang), sinf(ang));
}

// ---------------------------------------------------------------- GEMM core
__device__ __forceinline__ void gemm_mainloop(const short* __restrict__ A,
                                              const short* __restrict__ B,
                                              short (*Al)[40], short (*Bl)[40],
                                              int m0, int n0, int t,
                                              f32x4 acc[4][4]) {
    const int wave = t >> 6, lane = t & 63;
    const int wm = (wave >> 1) * 64, wn = (wave & 1) * 64;
    const int l15 = lane & 15, lg = lane >> 4;
    for (int k0 = 0; k0 < DM; k0 += 32) {
        __syncthreads();
#pragma unroll
        for (int i = 0; i < 2; ++i) {
            int c = t + i * 256;
            int row = c >> 2, kg = c & 3;
            *reinterpret_cast<short8*>(&Al[row][kg * 8]) =
                *reinterpret_cast<const short8*>(&A[(m0 + row) * DM + k0 + kg * 8]);
            *reinterpret_cast<short8*>(&Bl[row][kg * 8]) =
                *reinterpret_cast<const short8*>(&B[(n0 + row) * DM + k0 + kg * 8]);
        }
        __syncthreads();
        short8 af[4], bf[4];
#pragma unroll
        for (int m = 0; m < 4; ++m)
            af[m] = *reinterpret_cast<const short8*>(&Al[wm + m * 16 + l15][lg * 8]);
#pragma unroll
        for (int n = 0; n < 4; ++n)
            bf[n] = *reinterpret_cast<const short8*>(&Bl[wn + n * 16 + l15][lg * 8]);
#pragma unroll
        for (int m = 0; m < 4; ++m)
#pragma unroll
            for (int n = 0; n < 4; ++n)
                acc[m][n] = MFMA16(af[m], bf[n], acc[m][n]);
    }
}

// QKV projection + fused RoPE (+ 1/8*log2e scale on Q). grid = (6, 32, 3)
__global__ __launch_bounds__(256) void gemm_qkv_k(
    const short* __restrict__ Xbf, const short* __restrict__ Wq,
    const short* __restrict__ Wk, const short* __restrict__ Wv,
    const float2* __restrict__ rt,
    short* __restrict__ Q, short* __restrict__ K, short* __restrict__ V) {
    __shared__ __align__(16) short Al[128][40];
    __shared__ __align__(16) short Bl[128][40];
    const int mat = blockIdx.z;
    const short* B = mat == 0 ? Wq : (mat == 1 ? Wk : Wv);
    short* Out = mat == 0 ? Q : (mat == 1 ? K : V);
    const int m0 = blockIdx.y * 128, n0 = blockIdx.x * 128;
    const int t = threadIdx.x;
    f32x4 acc[4][4] = {};
    gemm_mainloop(Xbf, B, Al, Bl, m0, n0, t, acc);
    const int wave = t >> 6, lane = t & 63;
    const int wm = (wave >> 1) * 64, wn = (wave & 1) * 64;
    const int l15 = lane & 15, lg = lane >> 4;
    const bool dorope = (mat < 2);
#pragma unroll
    for (int m = 0; m < 4; ++m) {
#pragma unroll
        for (int n = 0; n < 4; ++n) {
            int col = n0 + wn + n * 16 + l15;
            int h = col >> 6, d = col & 63;
#pragma unroll
            for (int j = 0; j < 4; ++j) {
                int srow = m0 + wm + m * 16 + lg * 4 + j;
                float v = acc[m][n][j];
                float other = __shfl_xor(v, 1);
                if (dorope) {
                    float2 cs = rt[srow * 32 + (d >> 1)];
                    v = (d & 1) ? (other * cs.y + v * cs.x)
                                : (v * cs.x - other * cs.y);
                }
                if (mat == 0) v *= 0.125f * 1.44269504088896f;  // 1/sqrt(dk) * log2(e)
                Out[(h * S_LEN + srow) * DKH + d] = f2bf(v);
            }
        }
    }
}

// Output projection. grid = (6, 32)
__global__ __launch_bounds__(256) void gemm_out_k(const short* __restrict__ Ab,
                                                  const short* __restrict__ Wo,
                                                  float* __restrict__ out) {
    __shared__ __align__(16) short Al[128][40];
    __shared__ __align__(16) short Bl[128][40];
    const int m0 = blockIdx.y * 128, n0 = blockIdx.x * 128;
    const int t = threadIdx.x;
    f32x4 acc[4][4] = {};
    gemm_mainloop(Ab, Wo, Al, Bl, m0, n0, t, acc);
    const int wave = t >> 6, lane = t & 63;
    const int wm = (wave >> 1) * 64, wn = (wave & 1) * 64;
    const int l15 = lane & 15, lg = lane >> 4;
#pragma unroll
    for (int m = 0; m < 4; ++m)
#pragma unroll
        for (int n = 0; n < 4; ++n)
#pragma unroll
            for (int j = 0; j < 4; ++j) {
                int srow = m0 + wm + m * 16 + lg * 4 + j;
                int col = n0 + wn + n * 16 + l15;
                out[srow * DM + col] = acc[m][n][j];
            }
}

// V (H,S,64) -> Vt (H,64,S). grid = (12, 64)
__global__ __launch_bounds__(256) void transpose_v_k(const short* __restrict__ V,
                                                     short* __restrict__ Vt) {
    __shared__ __align__(16) short T[64][72];
    const int h = blockIdx.x, sb = blockIdx.y;
    const int t = threadIdx.x;
    const int s0 = sb * 64;
#pragma unroll
    for (int i = 0; i < 2; ++i) {
        int c = t + i * 256;
        int sr = c >> 3, dg = c & 7;
        short8 v = *reinterpret_cast<const short8*>(&V[(h * S_LEN + s0 + sr) * DKH + dg * 8]);
#pragma unroll
        for (int e = 0; e < 8; ++e) T[dg * 8 + e][sr] = v[e];
    }
    __syncthreads();
#pragma unroll
    for (int i = 0; i < 2; ++i) {
        int c = t + i * 256;
        int dr = c >> 3, sg = c & 7;
        *reinterpret_cast<short8*>(&Vt[(h * DKH + dr) * S_LEN + s0 + sg * 8]) =
            *reinterpret_cast<const short8*>(&T[dr][sg * 8]);
    }
}

// ---------------------------------------------------------------- attention
// Stage a 64x64 bf16 tile (8KB) into LDS via global_load_lds; XOR chunk
// swizzle applied on the GLOBAL source (linear LDS dest, rule #21).
__device__ __forceinline__ void stage64(const short* __restrict__ gRow0,
                                        int rowStride, short* lbuf,
                                        int wave, int lane) {
#pragma unroll
    for (int i = 0; i < 2; ++i) {
        int c = wave + i * 4;                     // 1KB chunk 0..7
        int row = c * 8 + (lane >> 3);            // tile row 0..63
        int gch = (lane & 7) ^ (lane >> 3);       // swizzled 16B chunk in row
        const short* src = gRow0 + (long)row * rowStride + gch * 8;
        short* dst = lbuf + c * 512 + lane * 8;   // linear: row*64 + chunk*8
        __builtin_amdgcn_global_load_lds(
            (const __attribute__((address_space(1))) void*)src,
            (__attribute__((address_space(3))) void*)dst, 16, 0, 0);
    }
}

// Swapped-operand causal flash attention. grid = 64*12 (heavy-first),
// 4 waves, 64 q-rows/block, 16 q-rows/wave, KV tile 64, double-buffered.
// S^T = mfma(K,Q): lane (l15,lg) holds S[kv=n*16+lg*4+j][q=l15] -> row
// reduction is 15 in-register ops + 2 shuffles. O^T = mfma(V,P).
__global__ __launch_bounds__(256) void attn_k(const short* __restrict__ Q,
                                              const short* __restrict__ K,
                                              const short* __restrict__ Vt,
                                              short* __restrict__ Aout) {
    const int bx = blockIdx.x;
    const int h = bx % NH;
    const int qb = (S_LEN / 64 - 1) - (bx / NH);    // heaviest blocks first
    const int t = threadIdx.x;
    const int wave = t >> 6, lane = t & 63;
    const int l15 = lane & 15, lg = lane >> 4;
    const int q0w = qb * 64 + wave * 16;

    __shared__ __align__(16) short KVl[2][2][64][64];  // [buf][K/V][row][col]
    __shared__ __align__(16) short Pl[4][16][76];

    short8 qf[2];
#pragma unroll
    for (int ks = 0; ks < 2; ++ks)
        qf[ks] = *reinterpret_cast<const short8*>(
            &Q[(h * S_LEN + q0w + l15) * DKH + ks * 32 + lg * 8]);

    f32x4 o[4] = {};
    float mrun = -1e30f, lrun = 0.f;

    const int nt = qb + 1;
    stage64(&K[(size_t)h * S_LEN * DKH], DKH, &KVl[0][0][0][0], wave, lane);
    stage64(&Vt[(size_t)h * DKH * S_LEN], S_LEN, &KVl[0][1][0][0], wave, lane);
    __syncthreads();
    int cur = 0;

    for (int tile = 0; tile < nt; ++tile) {
        const int kv0 = tile * 64;
        if (tile + 1 < nt) {
            const int kvn = kv0 + 64;
            stage64(&K[((size_t)h * S_LEN + kvn) * DKH], DKH, &KVl[cur ^ 1][0][0][0], wave, lane);
            stage64(&Vt[(size_t)h * DKH * S_LEN + kvn], S_LEN, &KVl[cur ^ 1][1][0][0], wave, lane);
        }
        const char* Kb = (const char*)&KVl[cur][0][0][0];
        const char* Vb = (const char*)&KVl[cur][1][0][0];

        // ---- S^T = K Q^T (Q pre-scaled by 1/8*log2e)
        f32x4 s[4] = {};
#pragma unroll
        for (int ks = 0; ks < 2; ++ks)
#pragma unroll
            for (int n = 0; n < 4; ++n) {
                int r = n * 16 + l15;
                int c8 = (ks * 4 + lg) ^ (r & 7);
                short8 kf = *reinterpret_cast<const short8*>(Kb + r * 128 + c8 * 16);
                s[n] = MFMA16(kf, qf[ks], s[n]);
            }

        // ---- causal mask (only the diagonal tile needs it)
        if (tile == qb) {
            const int q = q0w + l15;
#pragma unroll
            for (int n = 0; n < 4; ++n)
#pragma unroll
                for (int j = 0; j < 4; ++j)
                    if (kv0 + n * 16 + lg * 4 + j > q) s[n][j] = -1e30f;
        }

        // ---- online softmax: 16 values in-register + 2 shuffles
        float mt = fmaxf(fmaxf(fmaxf(s[0][0], s[0][1]), fmaxf(s[0][2], s[0][3])),
                         fmaxf(fmaxf(s[1][0], s[1][1]), fmaxf(s[1][2], s[1][3])));
        mt = fmaxf(mt, fmaxf(fmaxf(fmaxf(s[2][0], s[2][1]), fmaxf(s[2][2], s[2][3])),
                             fmaxf(fmaxf(s[3][0], s[3][1]), fmaxf(s[3][2], s[3][3]))));
        mt = fmaxf(mt, __shfl_xor(mt, 16));
        mt = fmaxf(mt, __shfl_xor(mt, 32));
        float mnew = fmaxf(mrun, mt);
        float alpha = exp2f(mrun - mnew);
        mrun = mnew;
        float rs = 0.f;
#pragma unroll
        for (int n = 0; n < 4; ++n)
#pragma unroll
            for (int j = 0; j < 4; ++j) {
                float p = exp2f(s[n][j] - mnew);
                s[n][j] = p;
                rs += p;
            }
        rs += __shfl_xor(rs, 16);
        rs += __shfl_xor(rs, 32);
        lrun = lrun * alpha + rs;
#pragma unroll
        for (int n = 0; n < 4; ++n)
#pragma unroll
            for (int j = 0; j < 4; ++j) o[n][j] *= alpha;

        // ---- P^T -> LDS (4x ds_write_b64), re-read as B-frag (2x b128)
#pragma unroll
        for (int n = 0; n < 4; ++n) {
            short4 pk;
            pk.x = f2bf(s[n][0]); pk.y = f2bf(s[n][1]);
            pk.z = f2bf(s[n][2]); pk.w = f2bf(s[n][3]);
            *reinterpret_cast<short4*>(&Pl[wave][l15][n * 16 + lg * 4]) = pk;
        }
#pragma unroll
        for (int ks = 0; ks < 2; ++ks) {
            short8 pa = *reinterpret_cast<const short8*>(&Pl[wave][l15][ks * 32 + lg * 8]);
#pragma unroll
            for (int n = 0; n < 4; ++n) {
                int r = n * 16 + l15;
                int c8 = (ks * 4 + lg) ^ (r & 7);
                short8 vf = *reinterpret_cast<const short8*>(Vb + r * 128 + c8 * 16);
                o[n] = MFMA16(vf, pa, o[n]);   // O^T[d, q]
            }
        }
        __syncthreads();
        cur ^= 1;
    }

    // ---- O^T -> LDS transpose (reuse KV buffers) -> coalesced store
    float inv = 1.f / lrun;
    float* Ol = (float*)&KVl[0][0][0][0] + wave * (16 * 68);
#pragma unroll
    for (int n = 0; n < 4; ++n) {
        float4 w;
        w.x = o[n][0] * inv; w.y = o[n][1] * inv;
        w.z = o[n][2] * inv; w.w = o[n][3] * inv;
        *reinterpret_cast<float4*>(&Ol[l15 * 68 + n * 16 + lg * 4]) = w;
    }
    __syncthreads();
#pragma unroll
    for (int kk = 0; kk < 4; ++kk) {
        int r = lane >> 2, c0 = (lane & 3) * 4 + kk * 16;
        float4 v = *reinterpret_cast<const float4*>(&Ol[r * 68 + c0]);
        short4 b;
        b.x = f2bf(v.x); b.y = f2bf(v.y); b.z = f2bf(v.z); b.w = f2bf(v.w);
        *reinterpret_cast<short4*>(
            &Aout[(size_t)(q0w + r) * DM + h * DKH + c0]) = b;
    }
}

// ---------------------------------------------------------------- launcher
extern "C" void kernel_launch(void* const* d_in, const int* in_sizes, int n_in,
                              void* d_out, int out_size, void* d_ws, size_t ws_size,
                              hipStream_t stream) {
    const float* X  = (const float*)d_in[0];
    const int*   pos = (const int*)d_in[1];
    const float* Wq = (const float*)d_in[2];
    const float* Wk = (const float*)d_in[3];
    const float* Wv = (const float*)d_in[4];
    const float* Wo = (const float*)d_in[5];
    float* out = (float*)d_out;

    char* ws = (char*)d_ws;
    short* Xbf = (short*)ws;  ws += (size_t)S_LEN * DM * 2;
    short* Wqb = (short*)ws;  ws += (size_t)DM * DM * 2;
    short* Wkb = (short*)ws;  ws += (size_t)DM * DM * 2;
    short* Wvb = (short*)ws;  ws += (size_t)DM * DM * 2;
    short* Wob = (short*)ws;  ws += (size_t)DM * DM * 2;
    float2* rt = (float2*)ws; ws += (size_t)S_LEN * 32 * 8;
    short* Qb  = (short*)ws;  ws += (size_t)NH * S_LEN * DKH * 2;
    short* Kb  = (short*)ws;  ws += (size_t)NH * S_LEN * DKH * 2;
    short* Vb  = (short*)ws;  ws += (size_t)NH * S_LEN * DKH * 2;
    short* Vtb = (short*)ws;  ws += (size_t)NH * S_LEN * DKH * 2;
    short* Ab  = (short*)ws;  ws += (size_t)S_LEN * DM * 2;

    to_bf16_k<<<(S_LEN * DM / 4 + 255) / 256, 256, 0, stream>>>(X, Xbf, S_LEN * DM);
    to_bf16_k<<<(DM * DM / 4 + 255) / 256, 256, 0, stream>>>(Wq, Wqb, DM * DM);
    to_bf16_k<<<(DM * DM / 4 + 255) / 256, 256, 0, stream>>>(Wk, Wkb, DM * DM);
    to_bf16_k<<<(DM * DM / 4 + 255) / 256, 256, 0, stream>>>(Wv, Wvb, DM * DM);
    to_bf16_k<<<(DM * DM / 4 + 255) / 256, 256, 0, stream>>>(Wo, Wob, DM * DM);
    rope_table_k<<<(S_LEN * 32 + 255) / 256, 256, 0, stream>>>(pos, rt);

    gemm_qkv_k<<<dim3(6, 32, 3), 256, 0, stream>>>(Xbf, Wqb, Wkb, Wvb, rt, Qb, Kb, Vb);
    transpose_v_k<<<dim3(NH, 64), 256, 0, stream>>>(Vb, Vtb);
    attn_k<<<dim3(64 * NH), 256, 0, stream>>>(Qb, Kb, Vtb, Ab);
    gemm_out_k<<<dim3(6, 32), 256, 0, stream>>>(Ab, Wob, out);
}

// Round 4
// 168.999 us; speedup vs baseline: 2.4972x; 1.0374x over previous
//
#include <hip/hip_runtime.h>
#include <hip/hip_bf16.h>

#define S_LEN 4096
#define DM    768
#define NH    12
#define DKH   64

typedef __attribute__((ext_vector_type(8))) short short8;
typedef __attribute__((ext_vector_type(4))) float f32x4;

__device__ __forceinline__ short f2bf(float f) {
    union { float f; unsigned u; } v; v.f = f;
    unsigned r = (v.u + 0x7FFFu + ((v.u >> 16) & 1u)) >> 16;
    return (short)r;
}

#define MFMA16(a, b, c) __builtin_amdgcn_mfma_f32_16x16x32_bf16((a), (b), (c), 0, 0, 0)

// ---------------------------------------------------------------- converts
__global__ __launch_bounds__(256) void to_bf16_k(const float* __restrict__ src,
                                                 short* __restrict__ dst, int n) {
    int i = (blockIdx.x * 256 + threadIdx.x) * 4;
    if (i >= n) return;
    float4 v = *reinterpret_cast<const float4*>(src + i);
    short4 o;
    o.x = f2bf(v.x); o.y = f2bf(v.y); o.z = f2bf(v.z); o.w = f2bf(v.w);
    *reinterpret_cast<short4*>(dst + i) = o;
}

__global__ __launch_bounds__(256) void rope_table_k(const int* __restrict__ pos,
                                                    float2* __restrict__ rt) {
    int idx = blockIdx.x * 256 + threadIdx.x;
    if (idx >= S_LEN * 32) return;
    int s = idx >> 5, i = idx & 31;
    int p = pos[s]; p = p < 0 ? 0 : (p > 4095 ? 4095 : p);
    double inv = pow(10000.0, -(double)i / 32.0);
    float ang = (float)((double)p * inv);
    rt[idx] = make_float2(cosf(ang), sinf(ang));
}

// ---------------------------------------------------------------- GEMM core
// m97 structure: 128x128 tile, BK=32, global_load_lds(16B) staging with
// XOR-chunk swizzle on the GLOBAL source (linear LDS dest, rule #21).
// LDS chunk m of row r holds global chunk m ^ (r&3); reads XOR the same.
__device__ __forceinline__ void gemm_mainloop(const short* __restrict__ A,
                                              const short* __restrict__ B,
                                              short* Al, short* Bl,
                                              int m0, int n0, int t,
                                              f32x4 acc[4][4]) {
    const int wave = t >> 6, lane = t & 63;
    const int wm = (wave >> 1) * 64, wn = (wave & 1) * 64;
    const int l15 = lane & 15, lg = lane >> 4;
    const int srow = lane >> 2;                 // staging row-in-16 (0..15)
    const int gca = (lane & 3) ^ (srow & 3);    // swizzled global chunk
    const int c8a = lg ^ (l15 & 3);             // swizzled read chunk
    short* dstA0 = Al + (wave * 2 + 0) * 512 + lane * 8;
    short* dstA1 = Al + (wave * 2 + 1) * 512 + lane * 8;
    short* dstB0 = Bl + (wave * 2 + 0) * 512 + lane * 8;
    short* dstB1 = Bl + (wave * 2 + 1) * 512 + lane * 8;
    const int ra0 = (wave * 2 + 0) * 16 + srow;
    const int ra1 = (wave * 2 + 1) * 16 + srow;
    for (int k0 = 0; k0 < DM; k0 += 32) {
        __syncthreads();
        __builtin_amdgcn_global_load_lds(
            (const __attribute__((address_space(1))) void*)&A[(m0 + ra0) * DM + k0 + gca * 8],
            (__attribute__((address_space(3))) void*)dstA0, 16, 0, 0);
        __builtin_amdgcn_global_load_lds(
            (const __attribute__((address_space(1))) void*)&A[(m0 + ra1) * DM + k0 + gca * 8],
            (__attribute__((address_space(3))) void*)dstA1, 16, 0, 0);
        __builtin_amdgcn_global_load_lds(
            (const __attribute__((address_space(1))) void*)&B[(n0 + ra0) * DM + k0 + gca * 8],
            (__attribute__((address_space(3))) void*)dstB0, 16, 0, 0);
        __builtin_amdgcn_global_load_lds(
            (const __attribute__((address_space(1))) void*)&B[(n0 + ra1) * DM + k0 + gca * 8],
            (__attribute__((address_space(3))) void*)dstB1, 16, 0, 0);
        __syncthreads();   // compiler drains vmcnt before barrier
        short8 af[4], bf[4];
#pragma unroll
        for (int m = 0; m < 4; ++m)
            af[m] = *reinterpret_cast<const short8*>(Al + (wm + m * 16 + l15) * 32 + c8a * 8);
#pragma unroll
        for (int n = 0; n < 4; ++n)
            bf[n] = *reinterpret_cast<const short8*>(Bl + (wn + n * 16 + l15) * 32 + c8a * 8);
#pragma unroll
        for (int m = 0; m < 4; ++m)
#pragma unroll
            for (int n = 0; n < 4; ++n)
                acc[m][n] = MFMA16(af[m], bf[n], acc[m][n]);
    }
}

// QKV projection + fused RoPE (+ 1/8*log2e on Q) + fused V-transpose.
// grid = (6, 32, 3)
__global__ __launch_bounds__(256) void gemm_qkv_k(
    const short* __restrict__ Xbf, const short* __restrict__ Wq,
    const short* __restrict__ Wk, const short* __restrict__ Wv,
    const float2* __restrict__ rt,
    short* __restrict__ Q, short* __restrict__ K, short* __restrict__ Vt) {
    __shared__ __align__(16) short Al[128 * 32];
    __shared__ __align__(16) short Bl[128 * 32];
    const int mat = blockIdx.z;
    const short* B = mat == 0 ? Wq : (mat == 1 ? Wk : Wv);
    const int m0 = blockIdx.y * 128, n0 = blockIdx.x * 128;
    const int t = threadIdx.x;
    f32x4 acc[4][4] = {};
    gemm_mainloop(Xbf, B, Al, Bl, m0, n0, t, acc);
    const int wave = t >> 6, lane = t & 63;
    const int wm = (wave >> 1) * 64, wn = (wave & 1) * 64;
    const int l15 = lane & 15, lg = lane >> 4;
    if (mat < 2) {
        short* Out = mat == 0 ? Q : K;
        const float qs = 0.125f * 1.44269504088896f;  // 1/sqrt(dk) * log2(e)
#pragma unroll
        for (int m = 0; m < 4; ++m) {
#pragma unroll
            for (int n = 0; n < 4; ++n) {
                int col = n0 + wn + n * 16 + l15;
                int h = col >> 6, d = col & 63;
#pragma unroll
                for (int j = 0; j < 4; ++j) {
                    int srow = m0 + wm + m * 16 + lg * 4 + j;
                    float v = acc[m][n][j];
                    float other = __shfl_xor(v, 1);
                    float2 cs = rt[srow * 32 + (d >> 1)];
                    v = (d & 1) ? (other * cs.y + v * cs.x)
                                : (v * cs.x - other * cs.y);
                    if (mat == 0) v *= qs;
                    Out[(h * S_LEN + srow) * DKH + d] = f2bf(v);
                }
            }
        }
    } else {
        // V: write transposed (H, 64, S) directly
#pragma unroll
        for (int m = 0; m < 4; ++m)
#pragma unroll
            for (int n = 0; n < 4; ++n) {
                int col = n0 + wn + n * 16 + l15;
                int h = col >> 6, d = col & 63;
                int srow0 = m0 + wm + m * 16 + lg * 4;
                short4 b;
                b.x = f2bf(acc[m][n][0]); b.y = f2bf(acc[m][n][1]);
                b.z = f2bf(acc[m][n][2]); b.w = f2bf(acc[m][n][3]);
                *reinterpret_cast<short4*>(&Vt[(size_t)(h * DKH + d) * S_LEN + srow0]) = b;
            }
    }
}

// Output projection. grid = (6, 32)
__global__ __launch_bounds__(256) void gemm_out_k(const short* __restrict__ Ab,
                                                  const short* __restrict__ Wo,
                                                  float* __restrict__ out) {
    __shared__ __align__(16) short Al[128 * 32];
    __shared__ __align__(16) short Bl[128 * 32];
    const int m0 = blockIdx.y * 128, n0 = blockIdx.x * 128;
    const int t = threadIdx.x;
    f32x4 acc[4][4] = {};
    gemm_mainloop(Ab, Wo, Al, Bl, m0, n0, t, acc);
    const int wave = t >> 6, lane = t & 63;
    const int wm = (wave >> 1) * 64, wn = (wave & 1) * 64;
    const int l15 = lane & 15, lg = lane >> 4;
#pragma unroll
    for (int m = 0; m < 4; ++m)
#pragma unroll
        for (int n = 0; n < 4; ++n)
#pragma unroll
            for (int j = 0; j < 4; ++j) {
                int srow = m0 + wm + m * 16 + lg * 4 + j;
                int col = n0 + wn + n * 16 + l15;
                out[srow * DM + col] = acc[m][n][j];
            }
}

// ---------------------------------------------------------------- attention
__device__ __forceinline__ void stage64(const short* __restrict__ gRow0,
                                        int rowStride, short* lbuf,
                                        int wave, int lane) {
#pragma unroll
    for (int i = 0; i < 2; ++i) {
        int c = wave + i * 4;                     // 1KB chunk 0..7
        int row = c * 8 + (lane >> 3);            // tile row 0..63
        int gch = (lane & 7) ^ (lane >> 3);       // swizzled 16B chunk in row
        const short* src = gRow0 + (long)row * rowStride + gch * 8;
        short* dst = lbuf + c * 512 + lane * 8;   // linear: row*64 + chunk*8
        __builtin_amdgcn_global_load_lds(
            (const __attribute__((address_space(1))) void*)src,
            (__attribute__((address_space(3))) void*)dst, 16, 0, 0);
    }
}

// Swapped-operand causal flash attention. grid = 64*12 (heavy-first),
// 4 waves, 64 q-rows/block, 16 q-rows/wave, KV tile 64, double-buffered.
__global__ __launch_bounds__(256) void attn_k(const short* __restrict__ Q,
                                              const short* __restrict__ K,
                                              const short* __restrict__ Vt,
                                              short* __restrict__ Aout) {
    const int bx = blockIdx.x;
    const int h = bx % NH;
    const int qb = (S_LEN / 64 - 1) - (bx / NH);    // heaviest blocks first
    const int t = threadIdx.x;
    const int wave = t >> 6, lane = t & 63;
    const int l15 = lane & 15, lg = lane >> 4;
    const int q0w = qb * 64 + wave * 16;

    __shared__ __align__(16) short KVl[2][2][64][64];
    __shared__ __align__(16) short Pl[4][16][76];

    short8 qf[2];
#pragma unroll
    for (int ks = 0; ks < 2; ++ks)
        qf[ks] = *reinterpret_cast<const short8*>(
            &Q[(h * S_LEN + q0w + l15) * DKH + ks * 32 + lg * 8]);

    f32x4 o[4] = {};
    float mrun = -1e30f, lrun = 0.f;

    const int nt = qb + 1;
    stage64(&K[(size_t)h * S_LEN * DKH], DKH, &KVl[0][0][0][0], wave, lane);
    stage64(&Vt[(size_t)h * DKH * S_LEN], S_LEN, &KVl[0][1][0][0], wave, lane);
    __syncthreads();
    int cur = 0;

    for (int tile = 0; tile < nt; ++tile) {
        const int kv0 = tile * 64;
        if (tile + 1 < nt) {
            const int kvn = kv0 + 64;
            stage64(&K[((size_t)h * S_LEN + kvn) * DKH], DKH, &KVl[cur ^ 1][0][0][0], wave, lane);
            stage64(&Vt[(size_t)h * DKH * S_LEN + kvn], S_LEN, &KVl[cur ^ 1][1][0][0], wave, lane);
        }
        const char* Kb = (const char*)&KVl[cur][0][0][0];
        const char* Vb = (const char*)&KVl[cur][1][0][0];

        // ---- S^T = K Q^T (Q pre-scaled by 1/8*log2e)
        f32x4 s[4] = {};
        __builtin_amdgcn_s_setprio(1);
#pragma unroll
        for (int ks = 0; ks < 2; ++ks)
#pragma unroll
            for (int n = 0; n < 4; ++n) {
                int r = n * 16 + l15;
                int c8 = (ks * 4 + lg) ^ (r & 7);
                short8 kf = *reinterpret_cast<const short8*>(Kb + r * 128 + c8 * 16);
                s[n] = MFMA16(kf, qf[ks], s[n]);
            }
        __builtin_amdgcn_s_setprio(0);

        // ---- causal mask (diagonal tile only)
        if (tile == qb) {
            const int q = q0w + l15;
#pragma unroll
            for (int n = 0; n < 4; ++n)
#pragma unroll
                for (int j = 0; j < 4; ++j)
                    if (kv0 + n * 16 + lg * 4 + j > q) s[n][j] = -1e30f;
        }

        // ---- online softmax: 16 in-register values + 2 shuffles
        float mt = fmaxf(fmaxf(fmaxf(s[0][0], s[0][1]), fmaxf(s[0][2], s[0][3])),
                         fmaxf(fmaxf(s[1][0], s[1][1]), fmaxf(s[1][2], s[1][3])));
        mt = fmaxf(mt, fmaxf(fmaxf(fmaxf(s[2][0], s[2][1]), fmaxf(s[2][2], s[2][3])),
                             fmaxf(fmaxf(s[3][0], s[3][1]), fmaxf(s[3][2], s[3][3]))));
        mt = fmaxf(mt, __shfl_xor(mt, 16));
        mt = fmaxf(mt, __shfl_xor(mt, 32));

        if (__all(mt <= mrun + 8.f)) {
            // defer-max: keep old max, no rescale (p bounded by 2^8)
            float rs = 0.f;
#pragma unroll
            for (int n = 0; n < 4; ++n)
#pragma unroll
                for (int j = 0; j < 4; ++j) {
                    float p = exp2f(s[n][j] - mrun);
                    s[n][j] = p;
                    rs += p;
                }
            rs += __shfl_xor(rs, 16);
            rs += __shfl_xor(rs, 32);
            lrun += rs;
        } else {
            float mnew = fmaxf(mrun, mt);
            float alpha = exp2f(mrun - mnew);
            float rs = 0.f;
#pragma unroll
            for (int n = 0; n < 4; ++n)
#pragma unroll
                for (int j = 0; j < 4; ++j) {
                    float p = exp2f(s[n][j] - mnew);
                    s[n][j] = p;
                    rs += p;
                }
            rs += __shfl_xor(rs, 16);
            rs += __shfl_xor(rs, 32);
            lrun = lrun * alpha + rs;
#pragma unroll
            for (int n = 0; n < 4; ++n)
#pragma unroll
                for (int j = 0; j < 4; ++j) o[n][j] *= alpha;
            mrun = mnew;
        }

        // ---- P^T -> LDS via v_cvt_pk_bf16_f32 (2 ops per 4 values)
#pragma unroll
        for (int n = 0; n < 4; ++n) {
            unsigned p0, p1;
            asm("v_cvt_pk_bf16_f32 %0, %1, %2" : "=v"(p0) : "v"(s[n][0]), "v"(s[n][1]));
            asm("v_cvt_pk_bf16_f32 %0, %1, %2" : "=v"(p1) : "v"(s[n][2]), "v"(s[n][3]));
            uint2 w; w.x = p0; w.y = p1;
            *reinterpret_cast<uint2*>(&Pl[wave][l15][n * 16 + lg * 4]) = w;
        }
        __builtin_amdgcn_s_setprio(1);
#pragma unroll
        for (int ks = 0; ks < 2; ++ks) {
            short8 pa = *reinterpret_cast<const short8*>(&Pl[wave][l15][ks * 32 + lg * 8]);
#pragma unroll
            for (int n = 0; n < 4; ++n) {
                int r = n * 16 + l15;
                int c8 = (ks * 4 + lg) ^ (r & 7);
                short8 vf = *reinterpret_cast<const short8*>(Vb + r * 128 + c8 * 16);
                o[n] = MFMA16(vf, pa, o[n]);   // O^T[d, q]
            }
        }
        __builtin_amdgcn_s_setprio(0);
        __syncthreads();
        cur ^= 1;
    }

    // ---- O^T -> LDS transpose (reuse KV buffers) -> coalesced store
    float inv = 1.f / lrun;
    float* Ol = (float*)&KVl[0][0][0][0] + wave * (16 * 68);
#pragma unroll
    for (int n = 0; n < 4; ++n) {
        float4 w;
        w.x = o[n][0] * inv; w.y = o[n][1] * inv;
        w.z = o[n][2] * inv; w.w = o[n][3] * inv;
        *reinterpret_cast<float4*>(&Ol[l15 * 68 + n * 16 + lg * 4]) = w;
    }
    __syncthreads();
#pragma unroll
    for (int kk = 0; kk < 4; ++kk) {
        int r = lane >> 2, c0 = (lane & 3) * 4 + kk * 16;
        float4 v = *reinterpret_cast<const float4*>(&Ol[r * 68 + c0]);
        short4 b;
        b.x = f2bf(v.x); b.y = f2bf(v.y); b.z = f2bf(v.z); b.w = f2bf(v.w);
        *reinterpret_cast<short4*>(
            &Aout[(size_t)(q0w + r) * DM + h * DKH + c0]) = b;
    }
}

// ---------------------------------------------------------------- launcher
extern "C" void kernel_launch(void* const* d_in, const int* in_sizes, int n_in,
                              void* d_out, int out_size, void* d_ws, size_t ws_size,
                              hipStream_t stream) {
    const float* X  = (const float*)d_in[0];
    const int*   pos = (const int*)d_in[1];
    const float* Wq = (const float*)d_in[2];
    const float* Wk = (const float*)d_in[3];
    const float* Wv = (const float*)d_in[4];
    const float* Wo = (const float*)d_in[5];
    float* out = (float*)d_out;

    char* ws = (char*)d_ws;
    short* Xbf = (short*)ws;  ws += (size_t)S_LEN * DM * 2;
    short* Wqb = (short*)ws;  ws += (size_t)DM * DM * 2;
    short* Wkb = (short*)ws;  ws += (size_t)DM * DM * 2;
    short* Wvb = (short*)ws;  ws += (size_t)DM * DM * 2;
    short* Wob = (short*)ws;  ws += (size_t)DM * DM * 2;
    float2* rt = (float2*)ws; ws += (size_t)S_LEN * 32 * 8;
    short* Qb  = (short*)ws;  ws += (size_t)NH * S_LEN * DKH * 2;
    short* Kb  = (short*)ws;  ws += (size_t)NH * S_LEN * DKH * 2;
    short* Vtb = (short*)ws;  ws += (size_t)NH * S_LEN * DKH * 2;
    short* Ab  = (short*)ws;  ws += (size_t)S_LEN * DM * 2;

    to_bf16_k<<<(S_LEN * DM / 4 + 255) / 256, 256, 0, stream>>>(X, Xbf, S_LEN * DM);
    to_bf16_k<<<(DM * DM / 4 + 255) / 256, 256, 0, stream>>>(Wq, Wqb, DM * DM);
    to_bf16_k<<<(DM * DM / 4 + 255) / 256, 256, 0, stream>>>(Wk, Wkb, DM * DM);
    to_bf16_k<<<(DM * DM / 4 + 255) / 256, 256, 0, stream>>>(Wv, Wvb, DM * DM);
    to_bf16_k<<<(DM * DM / 4 + 255) / 256, 256, 0, stream>>>(Wo, Wob, DM * DM);
    rope_table_k<<<(S_LEN * 32 + 255) / 256, 256, 0, stream>>>(pos, rt);

    gemm_qkv_k<<<dim3(6, 32, 3), 256, 0, stream>>>(Xbf, Wqb, Wkb, Wvb, rt, Qb, Kb, Vtb);
    attn_k<<<dim3(64 * NH), 256, 0, stream>>>(Qb, Kb, Vtb, Ab);
    gemm_out_k<<<dim3(6, 32), 256, 0, stream>>>(Ab, Wob, out);
}